// Round 17
// baseline (120.800 us; speedup 1.0000x reference)
//
#include <hip/hip_runtime.h>
#include <hip/hip_bf16.h>

// Problem constants
#define B_   2
#define N_   4096
#define DIM_ 768
#define H_   8
#define MROWS_ 8192   // B_*N_

typedef __bf16 bf16x8 __attribute__((ext_vector_type(8)));
typedef __bf16 bf16x4 __attribute__((ext_vector_type(4)));
typedef float  f32x4  __attribute__((ext_vector_type(4)));

static __device__ __forceinline__ f32x4 mfma16(bf16x8 a, bf16x8 b, f32x4 c) {
    return __builtin_amdgcn_mfma_f32_16x16x32_bf16(a, b, c, 0, 0, 0);
}
static __device__ __forceinline__ f32x4 mfma_fp8(long long a, long long b, f32x4 c) {
    return __builtin_amdgcn_mfma_f32_16x16x32_fp8_fp8(a, b, c, 0, 0, 0);
}

// async global->LDS, 16B per lane. LDS dst is wave-uniform base + lane*16.
#define GLDS16(g, l) \
    __builtin_amdgcn_global_load_lds((const __attribute__((address_space(1))) void*)(g), \
                                     (__attribute__((address_space(3))) void*)(l), 16, 0, 0)

// ---------------------------------------------------------------------------
// Kernel 1: fused prep. Blocks [0,6144): x f32 -> bf16. Blocks [6144,6528):
// LDS-tiled 64x64 weight transpose -> bf16.
__global__ __launch_bounds__(256) void prep_kernel(const float* __restrict__ x,
                                                   __bf16* __restrict__ xb,
                                                   const float* __restrict__ Wq,
                                                   const float* __restrict__ Wk,
                                                   const float* __restrict__ Wv,
                                                   const float* __restrict__ Wo,
                                                   __bf16* __restrict__ wt,
                                                   __bf16* __restrict__ wot) {
    __shared__ float tile[64][65];
    if (blockIdx.x < 6144) {
        int i = blockIdx.x * 256 + threadIdx.x;
        float4 f = reinterpret_cast<const float4*>(x)[i];
        bf16x4 o;
        o[0] = (__bf16)f.x; o[1] = (__bf16)f.y; o[2] = (__bf16)f.z; o[3] = (__bf16)f.w;
        reinterpret_cast<bf16x4*>(xb)[i] = o;
        return;
    }
    const int bix = blockIdx.x - 6144;
    const float* src;
    int src_ld, rbase, cbase, dst_ld, drow, dcol;
    __bf16* dst;
    if (bix < 288) {                       // Wq/Wk/Wv: [768][512]
        int m = bix / 96, t = bix - m * 96;
        int tr = t >> 3, tc = t & 7;
        src = (m == 0) ? Wq : ((m == 1) ? Wk : Wv);
        src_ld = 512; rbase = tr * 64; cbase = tc * 64;
        dst = wt; dst_ld = 768; drow = m * 512 + tc * 64; dcol = tr * 64;
    } else {                               // Wo: [512][768]
        int t = bix - 288;
        int tr = t / 12, tc = t - tr * 12;
        src = Wo; src_ld = 768; rbase = tr * 64; cbase = tc * 64;
        dst = wot; dst_ld = 512; drow = tc * 64; dcol = tr * 64;
    }
#pragma unroll
    for (int kk = 0; kk < 4; ++kk) {
        int idx = threadIdx.x + kk * 256;
        int r = idx >> 4, c = (idx & 15) << 2;
        float4 f = *reinterpret_cast<const float4*>(&src[(size_t)(rbase + r) * src_ld + cbase + c]);
        tile[r][c] = f.x; tile[r][c + 1] = f.y; tile[r][c + 2] = f.z; tile[r][c + 3] = f.w;
    }
    __syncthreads();
#pragma unroll
    for (int kk = 0; kk < 4; ++kk) {
        int idx = threadIdx.x + kk * 256;
        int r = idx >> 4, c = (idx & 15) << 2;
        bf16x4 ov;
        ov[0] = (__bf16)tile[c][r];     ov[1] = (__bf16)tile[c + 1][r];
        ov[2] = (__bf16)tile[c + 2][r]; ov[3] = (__bf16)tile[c + 3][r];
        *reinterpret_cast<bf16x4*>(&dst[(size_t)(drow + r) * dst_ld + dcol + c]) = ov;
    }
}

// ---------------------------------------------------------------------------
// m97-structure GEMM main loop: 128x128 tile, BK=32, 4 waves (2x2 of 64x64),
// global_load_lds(16B) double-buffered staging, 2-phase pipeline.
// C[i][j] = sum_k A[arow0+i][k] * Bt[bcol0+j][k];
// lane map: i = wr*64 + m*16 + lg*4 + r, j = wc*64 + n*16 + lr.
template<int KSTEPS>
__device__ __forceinline__ void gemm_tile_main(const __bf16* __restrict__ A, const int lda,
                                               const int arow0,
                                               const __bf16* __restrict__ Bt, const int ldb,
                                               const int bcol0,
                                               __bf16* __restrict__ abuf,
                                               __bf16* __restrict__ bbuf,
                                               f32x4 (&acc)[4][4]) {
    const int lane = threadIdx.x & 63, wave = threadIdx.x >> 6;
    const int lr = lane & 15, lg = lane >> 4;
    const int wr = wave >> 1, wc = wave & 1;

    const int cid0 = wave * 128 + lane;
    const int cid1 = cid0 + 64;
    const __bf16* sA0 = A  + (size_t)(arow0 + (cid0 >> 2)) * lda + (cid0 & 3) * 8;
    const __bf16* sA1 = A  + (size_t)(arow0 + (cid1 >> 2)) * lda + (cid1 & 3) * 8;
    const __bf16* sB0 = Bt + (size_t)(bcol0 + (cid0 >> 2)) * ldb + (cid0 & 3) * 8;
    const __bf16* sB1 = Bt + (size_t)(bcol0 + (cid1 >> 2)) * ldb + (cid1 & 3) * 8;

    auto stage = [&](int buf, int ks) {
        __bf16* da = abuf + buf * 4096 + wave * 1024;
        __bf16* db = bbuf + buf * 4096 + wave * 1024;
        GLDS16(sA0 + ks * 32, da);
        GLDS16(sA1 + ks * 32, da + 512);
        GLDS16(sB0 + ks * 32, db);
        GLDS16(sB1 + ks * 32, db + 512);
    };

    stage(0, 0);
    asm volatile("s_waitcnt vmcnt(0)" ::: "memory");
    __syncthreads();

    const int ar_off = (wr * 64 + lr) * 32 + lg * 8;
    const int br_off = (wc * 64 + lr) * 32 + lg * 8;

    int buf = 0;
    for (int ks = 0; ks < KSTEPS; ++ks) {
        if (ks + 1 < KSTEPS) stage(buf ^ 1, ks + 1);
        const __bf16* ab = abuf + buf * 4096 + ar_off;
        const __bf16* bb = bbuf + buf * 4096 + br_off;
        bf16x8 af[4], bfr[4];
#pragma unroll
        for (int m = 0; m < 4; ++m) af[m] = *reinterpret_cast<const bf16x8*>(ab + m * 512);
#pragma unroll
        for (int n = 0; n < 4; ++n) bfr[n] = *reinterpret_cast<const bf16x8*>(bb + n * 512);
#pragma unroll
        for (int m = 0; m < 4; ++m)
#pragma unroll
            for (int n = 0; n < 4; ++n)
                acc[m][n] = mfma16(af[m], bfr[n], acc[m][n]);
        asm volatile("s_waitcnt vmcnt(0)" ::: "memory");
        __syncthreads();
        buf ^= 1;
    }
}

// ---------------------------------------------------------------------------
// Kernel 3: QKV projection GEMM. 768 blocks (XCD-chunked).
// Q/K blocks (by<8): SWAPPED operands (A=wt, B=xb) so each lane's 4 r-values
// are 4 consecutive d -> one packed fp8x4 u32 store. V blocks: unswapped
// (r along tokens matches the transposed [B,H,64,N] layout's int store).
// Q pre-scaled by 0.125*log2(e). All outputs fp8 e4m3.
__global__ __launch_bounds__(256) void qkv_gemm_kernel(const __bf16* __restrict__ xb,
                                                       const __bf16* __restrict__ wt,
                                                       unsigned char* __restrict__ q,
                                                       unsigned char* __restrict__ k,
                                                       unsigned char* __restrict__ vt) {
    __shared__ __align__(16) __bf16 abuf[2 * 4096];
    __shared__ __align__(16) __bf16 bbuf[2 * 4096];

    const int bid = blockIdx.x;
    const int vb = (bid & 7) * 96 + (bid >> 3);
    const int by = vb % 12, bx = vb / 12;

    const int lane = threadIdx.x & 63, wave = threadIdx.x >> 6;
    const int lr = lane & 15, lg = lane >> 4;
    const int wr = wave >> 1, wc = wave & 1;

    const float QSCALE = 0.125f * 1.44269504089f;   // fold log2(e): softmax uses exp2
    f32x4 acc[4][4] = {};

    if (by < 8) {
        // ---- Q or K: swapped. C[c][token], c = qkv col, token = x row.
        gemm_tile_main<24>(wt, 768, by * 128, xb, 768, bx * 128, abuf, bbuf, acc);
        const bool isQ = (by < 4);
        unsigned char* dst = isQ ? q : k;
        const float scale = isQ ? QSCALE : 1.0f;
        const int cbase = by * 128 + wr * 64 - (isQ ? 0 : 512);
        const int tbase = bx * 128 + wc * 64;
#pragma unroll
        for (int m = 0; m < 4; ++m) {
            const int c = cbase + m * 16 + lg * 4;      // 4 consecutive d = c..c+3
            const int h = c >> 6, d4 = c & 63;
#pragma unroll
            for (int n = 0; n < 4; ++n) {
                const int token = tbase + n * 16 + lr;
                const size_t hb = (size_t)((token >> 12) * 8 + h);
                int w = 0;
                w = __builtin_amdgcn_cvt_pk_fp8_f32(acc[m][n][0] * scale, acc[m][n][1] * scale, w, 0);
                w = __builtin_amdgcn_cvt_pk_fp8_f32(acc[m][n][2] * scale, acc[m][n][3] * scale, w, 1);
                *reinterpret_cast<unsigned int*>(
                    &dst[(hb * 4096 + (token & 4095)) * 64 + d4]) = (unsigned int)w;
            }
        }
    } else {
        // ---- V: unswapped. C[token][c]; r-values = 4 consecutive tokens.
        gemm_tile_main<24>(xb, 768, bx * 128, wt, 768, by * 128, abuf, bbuf, acc);
        const int bi = (bx * 128) >> 12;
        const int nbase = (bx * 128) & 4095;
#pragma unroll
        for (int n = 0; n < 4; ++n) {
            const int col0 = by * 128 + wc * 64 + n * 16;
            const int h  = (col0 >> 6) & 7;
            const int d0 = (col0 & 63) + lr;
            const size_t hb = (size_t)(bi * 8 + h);
#pragma unroll
            for (int m = 0; m < 4; ++m) {
                const int nn = nbase + wr * 64 + m * 16 + lg * 4;
                int vv = 0;
                vv = __builtin_amdgcn_cvt_pk_fp8_f32(acc[m][n][0], acc[m][n][1], vv, 0);
                vv = __builtin_amdgcn_cvt_pk_fp8_f32(acc[m][n][2], acc[m][n][3], vv, 1);
                *reinterpret_cast<int*>(&vt[(hb * 64 + d0) * 4096 + nn]) = vv;
            }
        }
    }
}

// ---------------------------------------------------------------------------
// Kernel 4: flash attention, FP8 (round-15 version, verified fastest).
// 8 waves x 32q x 32k, 4 waves/SIMD, triple-buffered 4KB K/V slots,
// counted vmcnt(1), raw s_barrier, sigma-permuted K staging keeps P
// in-register; 16B-chunk XOR swizzle on staging source; b64 fragment reads.
__global__ __launch_bounds__(512, 4) void attn_kernel(const unsigned char* __restrict__ q,
                                                      const unsigned char* __restrict__ k,
                                                      const unsigned char* __restrict__ vt,
                                                      __bf16* __restrict__ o) {
    const int lane = threadIdx.x & 63, wave = threadIdx.x >> 6;
    const int lr = lane & 15, lg = lane >> 4;
    const int qg = wave >> 1, kh = wave & 1;

    const int bid  = blockIdx.x;
    const int vbid = (bid & 7) * 64 + (bid >> 3);
    const int qtile = vbid & 31;
    const int bh    = vbid >> 5;
    const int qbase = qtile * 128 + qg * 32;

    const unsigned char* Qh = q  + (size_t)bh * N_ * 64;
    const unsigned char* Kh = k  + (size_t)bh * N_ * 64;
    const unsigned char* Vh = vt + (size_t)bh * 64 * N_;

    __shared__ __align__(16) char smem[24576];
    char* kb0 = smem;            // 3 K slots x 4KB
    char* vb0 = smem + 12288;    // 3 V slots x 4KB

    // staging source offsets (per lane): K with row-sigma + chunk swizzle,
    // V with chunk swizzle only. chunk swizzle x(r) = (r&3)^((r>>2)&3).
    int ksrcOff = 0;
    size_t vsrcOff = 0;
    if (wave < 4) {
        int ci = wave * 64 + lane;
        int r = ci >> 2, c = ci & 3;
        int sig = ((r >> 4) & 1) * 32 + ((r >> 2) & 3) * 8 + ((r >> 5) & 1) * 4 + (r & 3);
        ksrcOff = sig * 64 + ((c ^ ((r & 3) ^ ((r >> 2) & 3))) << 4);
    } else {
        int ci = (wave - 4) * 64 + lane;
        int r = ci >> 2, c = ci & 3;
        vsrcOff = (size_t)r * 4096 + ((c ^ ((r & 3) ^ ((r >> 2) & 3))) << 4);
    }

    auto stageK = [&](int slot, int jt) {   // waves 0-3, 1 GLDS16 each
        if (wave < 4)
            GLDS16(Kh + (size_t)jt * 4096 + ksrcOff, kb0 + slot * 4096 + wave * 1024);
    };
    auto stageV = [&](int slot, int jt) {   // waves 4-7, 1 GLDS16 each
        if (wave >= 4)
            GLDS16(Vh + vsrcOff + jt * 64, vb0 + slot * 4096 + (wave - 4) * 1024);
    };

    // fragment read offsets (swizzled, b64)
    int kaddr[2][2], vaddr[4];
#pragma unroll
    for (int kc = 0; kc < 2; ++kc)
#pragma unroll
        for (int c2 = 0; c2 < 2; ++c2) {
            int row = (kh + 2 * c2) * 16 + lr;
            int x = (row & 3) ^ ((row >> 2) & 3);
            kaddr[kc][c2] = row * 64 + (((kc * 2 + (lg >> 1)) ^ x) << 4) + ((lg & 1) << 3);
        }
#pragma unroll
    for (int cbv = 0; cbv < 4; ++cbv) {
        int row = cbv * 16 + lr;
        int x = (row & 3) ^ ((row >> 2) & 3);
        vaddr[cbv] = row * 64 + (((kh * 2 + (lg >> 1)) ^ x) << 4) + ((lg & 1) << 3);
    }

    long long qf[2][2];
#pragma unroll
    for (int f = 0; f < 2; ++f)
#pragma unroll
        for (int kc = 0; kc < 2; ++kc)
            qf[f][kc] = *reinterpret_cast<const long long*>(
                Qh + (size_t)(qbase + f * 16 + lr) * 64 + kc * 32 + lg * 8);

    f32x4 acc[2][4] = {};
    f32x4 accl[2] = {};
    const long long ONES8 = 0x3838383838383838LL;   // 8x fp8 e4m3 1.0

    f32x4 s[2][2];         // 32q x 32k logits (s-slot groups kh, kh+2)
    long long pk[2];       // previous tile's P as fp8x8 PV A-fragments

    auto QK = [&](const char* kb) {
        __builtin_amdgcn_s_setprio(1);
#pragma unroll
        for (int kc = 0; kc < 2; ++kc) {
#pragma unroll
            for (int c2 = 0; c2 < 2; ++c2) {
                long long bk = *reinterpret_cast<const long long*>(kb + kaddr[kc][c2]);
#pragma unroll
                for (int f = 0; f < 2; ++f) {
                    if (kc == 0) s[f][c2] = mfma_fp8(bk, qf[f][0], {});
                    else         s[f][c2] = mfma_fp8(bk, qf[f][1], s[f][c2]);
                }
            }
        }
        __builtin_amdgcn_s_setprio(0);
    };
    auto EXP = [&]() {   // s -> pk (fp8); partial lsum via matrix pipe
#pragma unroll
        for (int f = 0; f < 2; ++f) {
            float p0 = __builtin_amdgcn_exp2f(s[f][0][0]);
            float p1 = __builtin_amdgcn_exp2f(s[f][0][1]);
            float p2 = __builtin_amdgcn_exp2f(s[f][0][2]);
            float p3 = __builtin_amdgcn_exp2f(s[f][0][3]);
            float p4 = __builtin_amdgcn_exp2f(s[f][1][0]);
            float p5 = __builtin_amdgcn_exp2f(s[f][1][1]);
            float p6 = __builtin_amdgcn_exp2f(s[f][1][2]);
            float p7 = __builtin_amdgcn_exp2f(s[f][1][3]);
            int lo = 0, hi = 0;
            lo = __builtin_amdgcn_cvt_pk_fp8_f32(p0, p1, lo, 0);
            lo = __builtin_amdgcn_cvt_pk_fp8_f32(p2, p3, lo, 1);
            hi = __builtin_amdgcn_cvt_pk_fp8_f32(p4, p5, hi, 0);
            hi = __builtin_amdgcn_cvt_pk_fp8_f32(p6, p7, hi, 1);
            pk[f] = (long long)(unsigned int)lo | ((long long)hi << 32);
            accl[f] = mfma_fp8(pk[f], ONES8, accl[f]);
        }
    };
    auto PV = [&](const char* vb) {   // consumes pk; V chunk kc = kh
        __builtin_amdgcn_s_setprio(1);
#pragma unroll
        for (int cbv = 0; cbv < 4; ++cbv) {
            long long bv = *reinterpret_cast<const long long*>(vb + vaddr[cbv]);
#pragma unroll
            for (int f = 0; f < 2; ++f)
                acc[f][cbv] = mfma_fp8(pk[f], bv, acc[f][cbv]);
        }
        __builtin_amdgcn_s_setprio(0);
    };

    auto kslotp = [&](int sl) { return (const char*)(kb0 + sl * 4096); };
    auto vslotp = [&](int sl) { return (const char*)(vb0 + sl * 4096); };

    // one pipelined iteration: stage K(t+2), V(t+1); compute tile t;
    // keep this iter's load (1/wave) in flight; raw barrier.
    auto ITER = [&](int kr, int kw, int ktile, int vr, int vw, int vtile) {
        stageK(kw, ktile);
        stageV(vw, vtile);
        QK(kslotp(kr));
        PV(vslotp(vr));
        EXP();
        asm volatile("s_waitcnt vmcnt(1)" ::: "memory");
        __builtin_amdgcn_s_barrier();
    };

    // ---- prologue: K(0)->k0, K(1)->k1, V(0)->v0; full drain.
    stageK(0, 0); stageK(1, 1); stageV(0, 0);
    asm volatile("s_waitcnt vmcnt(0)" ::: "memory");
    __builtin_amdgcn_s_barrier();

    // ---- iter 0 (no previous tile): stage K(2)->k2, V(1)->v1.
    stageK(2, 2); stageV(1, 1);
    QK(kslotp(0));
    EXP();
    asm volatile("s_waitcnt vmcnt(1)" ::: "memory");
    __builtin_amdgcn_s_barrier();

    // ---- iters 1..60, unrolled by 3 for compile-time slot rotation
    for (int t = 0; t < 20; ++t) {
        const int a = 3 * t + 1;
        ITER(1, 0, a + 2, 0, 2, a + 1);   // jt = a
        ITER(2, 1, a + 3, 1, 0, a + 2);   // jt = a+1
        ITER(0, 2, a + 4, 2, 1, a + 3);   // jt = a+2
    }
    // ---- jt = 61: stage K(63)->k0, V(62)->v2
    ITER(1, 0, 63, 0, 2, 62);

    // ---- jt = 62: only V(63) left to stage; full drain (tail discipline)
    stageV(0, 63);
    QK(kslotp(2));
    PV(vslotp(1));
    EXP();
    asm volatile("s_waitcnt vmcnt(0)" ::: "memory");
    __builtin_amdgcn_s_barrier();

    // ---- jt = 63
    QK(kslotp(0));
    PV(vslotp(2));
    EXP();
    asm volatile("s_waitcnt vmcnt(0)" ::: "memory");
    __builtin_amdgcn_s_barrier();

    // ---- final PV for tile 63 (V63 in v0)
    PV(vslotp(0));
    __syncthreads();     // all waves done with K/V buffers; LDS reusable

    // ---- cross-wave combine: kh=1 writes partials (acc bf16, lsum f32),
    // kh=0 combines and writes output.
    char* exa = smem + qg * 4096;            // acc partials: 64 lanes x 64B
    char* exl = smem + 16384 + qg * 2048;    // lsum partials: 64 lanes x 32B
    if (kh == 1) {
#pragma unroll
        for (int f = 0; f < 2; ++f) {
#pragma unroll
            for (int cbv = 0; cbv < 4; ++cbv) {
                bf16x4 p4;
#pragma unroll
                for (int r = 0; r < 4; ++r) p4[r] = (__bf16)acc[f][cbv][r];
                *reinterpret_cast<bf16x4*>(exa + lane * 64 + (f * 4 + cbv) * 8) = p4;
            }
            *reinterpret_cast<f32x4*>(exl + lane * 32 + f * 16) = accl[f];
        }
    }
    __syncthreads();

    if (kh == 0) {
        const int b = bh >> 3, h = bh & 7;
#pragma unroll
        for (int f = 0; f < 2; ++f) {
            f32x4 lp = *reinterpret_cast<const f32x4*>(exl + lane * 32 + f * 16);
            f32x4 inv;
#pragma unroll
            for (int r = 0; r < 4; ++r) inv[r] = 1.f / (accl[f][r] + lp[r]);
#pragma unroll
            for (int cbv = 0; cbv < 4; ++cbv) {
                bf16x4 ap = *reinterpret_cast<const bf16x4*>(exa + lane * 64 + (f * 4 + cbv) * 8);
#pragma unroll
                for (int r = 0; r < 4; ++r) {
                    const int row = b * N_ + qbase + f * 16 + lg * 4 + r;
                    o[(size_t)row * 512 + h * 64 + cbv * 16 + lr] =
                        (__bf16)((acc[f][cbv][r] + (float)ap[r]) * inv[r]);
                }
            }
        }
    }
}

// ---------------------------------------------------------------------------
// Kernel 5: output projection GEMM, SWAPPED operands (A=wot, B=ob) ->
// lane's 4 r-values = 4 consecutive out cols -> float4 store + float4 bias.
// 384 blocks. K=512.
__global__ __launch_bounds__(256) void out_gemm_kernel(const __bf16* __restrict__ ob,
                                                       const __bf16* __restrict__ wot,
                                                       const float* __restrict__ bo,
                                                       float* __restrict__ out) {
    __shared__ __align__(16) __bf16 abuf[2 * 4096];
    __shared__ __align__(16) __bf16 bbuf[2 * 4096];

    const int bid = blockIdx.x;
    const int vb = (bid & 7) * 48 + (bid >> 3);
    const int by = vb % 6, bx = vb / 6;

    f32x4 acc[4][4] = {};
    gemm_tile_main<16>(wot, 512, by * 128, ob, 512, bx * 128, abuf, bbuf, acc);

    const int lane = threadIdx.x & 63, wave = threadIdx.x >> 6;
    const int lr = lane & 15, lg = lane >> 4;
    const int wr = wave >> 1, wc = wave & 1;

    const int cbase = by * 128 + wr * 64;
    const int tbase = bx * 128 + wc * 64;
#pragma unroll
    for (int m = 0; m < 4; ++m) {
        const int col0 = cbase + m * 16 + lg * 4;
        const float4 b4 = *reinterpret_cast<const float4*>(&bo[col0]);
#pragma unroll
        for (int n = 0; n < 4; ++n) {
            const int token = tbase + n * 16 + lr;
            float4 ov;
            ov.x = acc[m][n][0] + b4.x;
            ov.y = acc[m][n][1] + b4.y;
            ov.z = acc[m][n][2] + b4.z;
            ov.w = acc[m][n][3] + b4.w;
            *reinterpret_cast<float4*>(&out[(size_t)token * 768 + col0]) = ov;
        }
    }
}

// ---------------------------------------------------------------------------
extern "C" void kernel_launch(void* const* d_in, const int* in_sizes, int n_in,
                              void* d_out, int out_size, void* d_ws, size_t ws_size,
                              hipStream_t stream) {
    const float* x  = (const float*)d_in[0];
    const float* Wq = (const float*)d_in[1];
    const float* Wk = (const float*)d_in[2];
    const float* Wv = (const float*)d_in[3];
    const float* Wo = (const float*)d_in[4];
    const float* bo = (const float*)d_in[5];
    float* out = (float*)d_out;

    char* ws = (char*)d_ws;
    __bf16* xb  = (__bf16*)(ws);                                  // 12,582,912
    __bf16* wt  = (__bf16*)(ws + 12582912);                       //  2,359,296
    __bf16* wot = (__bf16*)(ws + 12582912 + 2359296);             //    786,432
    char*   p0  = ws + 12582912 + 2359296 + 786432;               // 15,728,640
    unsigned char* qw  = (unsigned char*)(p0);                    //  4,194,304 (fp8)
    unsigned char* kw  = (unsigned char*)(p0 + 4194304);          //  4,194,304 (fp8)
    unsigned char* vtw = (unsigned char*)(p0 + 2 * 4194304);      //  4,194,304 (fp8)
    __bf16* obf = (__bf16*)(p0 + 3 * (size_t)4194304);            //  8,388,608
    // total ws use: ~36.7 MB

    prep_kernel<<<6528, 256, 0, stream>>>(x, xb, Wq, Wk, Wv, Wo, wt, wot);
    qkv_gemm_kernel<<<768, 256, 0, stream>>>(xb, wt, qw, kw, vtw);
    attn_kernel<<<512, 512, 0, stream>>>(qw, kw, vtw, obf);
    out_gemm_kernel<<<384, 256, 0, stream>>>(obf, wot, bo, out);
}

// Round 18
// 115.077 us; speedup vs baseline: 1.0497x; 1.0497x over previous
//
#include <hip/hip_runtime.h>
#include <hip/hip_bf16.h>

// Problem constants
#define B_   2
#define N_   4096
#define DIM_ 768
#define H_   8
#define MROWS_ 8192   // B_*N_

typedef __bf16 bf16x8 __attribute__((ext_vector_type(8)));
typedef __bf16 bf16x4 __attribute__((ext_vector_type(4)));
typedef float  f32x4  __attribute__((ext_vector_type(4)));

static __device__ __forceinline__ f32x4 mfma16(bf16x8 a, bf16x8 b, f32x4 c) {
    return __builtin_amdgcn_mfma_f32_16x16x32_bf16(a, b, c, 0, 0, 0);
}
static __device__ __forceinline__ f32x4 mfma_fp8(long long a, long long b, f32x4 c) {
    return __builtin_amdgcn_mfma_f32_16x16x32_fp8_fp8(a, b, c, 0, 0, 0);
}

// async global->LDS, 16B per lane. LDS dst is wave-uniform base + lane*16.
#define GLDS16(g, l) \
    __builtin_amdgcn_global_load_lds((const __attribute__((address_space(1))) void*)(g), \
                                     (__attribute__((address_space(3))) void*)(l), 16, 0, 0)

// ---------------------------------------------------------------------------
// Kernel 1: fused prep. Blocks [0,6144): x f32 -> bf16. Blocks [6144,6528):
// LDS-tiled 64x64 weight transpose -> bf16.
__global__ __launch_bounds__(256) void prep_kernel(const float* __restrict__ x,
                                                   __bf16* __restrict__ xb,
                                                   const float* __restrict__ Wq,
                                                   const float* __restrict__ Wk,
                                                   const float* __restrict__ Wv,
                                                   const float* __restrict__ Wo,
                                                   __bf16* __restrict__ wt,
                                                   __bf16* __restrict__ wot) {
    __shared__ float tile[64][65];
    if (blockIdx.x < 6144) {
        int i = blockIdx.x * 256 + threadIdx.x;
        float4 f = reinterpret_cast<const float4*>(x)[i];
        bf16x4 o;
        o[0] = (__bf16)f.x; o[1] = (__bf16)f.y; o[2] = (__bf16)f.z; o[3] = (__bf16)f.w;
        reinterpret_cast<bf16x4*>(xb)[i] = o;
        return;
    }
    const int bix = blockIdx.x - 6144;
    const float* src;
    int src_ld, rbase, cbase, dst_ld, drow, dcol;
    __bf16* dst;
    if (bix < 288) {                       // Wq/Wk/Wv: [768][512]
        int m = bix / 96, t = bix - m * 96;
        int tr = t >> 3, tc = t & 7;
        src = (m == 0) ? Wq : ((m == 1) ? Wk : Wv);
        src_ld = 512; rbase = tr * 64; cbase = tc * 64;
        dst = wt; dst_ld = 768; drow = m * 512 + tc * 64; dcol = tr * 64;
    } else {                               // Wo: [512][768]
        int t = bix - 288;
        int tr = t / 12, tc = t - tr * 12;
        src = Wo; src_ld = 768; rbase = tr * 64; cbase = tc * 64;
        dst = wot; dst_ld = 512; drow = tc * 64; dcol = tr * 64;
    }
#pragma unroll
    for (int kk = 0; kk < 4; ++kk) {
        int idx = threadIdx.x + kk * 256;
        int r = idx >> 4, c = (idx & 15) << 2;
        float4 f = *reinterpret_cast<const float4*>(&src[(size_t)(rbase + r) * src_ld + cbase + c]);
        tile[r][c] = f.x; tile[r][c + 1] = f.y; tile[r][c + 2] = f.z; tile[r][c + 3] = f.w;
    }
    __syncthreads();
#pragma unroll
    for (int kk = 0; kk < 4; ++kk) {
        int idx = threadIdx.x + kk * 256;
        int r = idx >> 4, c = (idx & 15) << 2;
        bf16x4 ov;
        ov[0] = (__bf16)tile[c][r];     ov[1] = (__bf16)tile[c + 1][r];
        ov[2] = (__bf16)tile[c + 2][r]; ov[3] = (__bf16)tile[c + 3][r];
        *reinterpret_cast<bf16x4*>(&dst[(size_t)(drow + r) * dst_ld + dcol + c]) = ov;
    }
}

// ---------------------------------------------------------------------------
// m97-structure GEMM main loop: 128x128 tile, BK=32, 4 waves (2x2 of 64x64),
// global_load_lds(16B) double-buffered staging, 2-phase pipeline.
template<int KSTEPS>
__device__ __forceinline__ void gemm_tile_main(const __bf16* __restrict__ A, const int lda,
                                               const int arow0,
                                               const __bf16* __restrict__ Bt, const int ldb,
                                               const int bcol0,
                                               __bf16* __restrict__ abuf,
                                               __bf16* __restrict__ bbuf,
                                               f32x4 (&acc)[4][4]) {
    const int lane = threadIdx.x & 63, wave = threadIdx.x >> 6;
    const int lr = lane & 15, lg = lane >> 4;
    const int wr = wave >> 1, wc = wave & 1;

    const int cid0 = wave * 128 + lane;
    const int cid1 = cid0 + 64;
    const __bf16* sA0 = A  + (size_t)(arow0 + (cid0 >> 2)) * lda + (cid0 & 3) * 8;
    const __bf16* sA1 = A  + (size_t)(arow0 + (cid1 >> 2)) * lda + (cid1 & 3) * 8;
    const __bf16* sB0 = Bt + (size_t)(bcol0 + (cid0 >> 2)) * ldb + (cid0 & 3) * 8;
    const __bf16* sB1 = Bt + (size_t)(bcol0 + (cid1 >> 2)) * ldb + (cid1 & 3) * 8;

    auto stage = [&](int buf, int ks) {
        __bf16* da = abuf + buf * 4096 + wave * 1024;
        __bf16* db = bbuf + buf * 4096 + wave * 1024;
        GLDS16(sA0 + ks * 32, da);
        GLDS16(sA1 + ks * 32, da + 512);
        GLDS16(sB0 + ks * 32, db);
        GLDS16(sB1 + ks * 32, db + 512);
    };

    stage(0, 0);
    asm volatile("s_waitcnt vmcnt(0)" ::: "memory");
    __syncthreads();

    const int ar_off = (wr * 64 + lr) * 32 + lg * 8;
    const int br_off = (wc * 64 + lr) * 32 + lg * 8;

    int buf = 0;
    for (int ks = 0; ks < KSTEPS; ++ks) {
        if (ks + 1 < KSTEPS) stage(buf ^ 1, ks + 1);
        const __bf16* ab = abuf + buf * 4096 + ar_off;
        const __bf16* bb = bbuf + buf * 4096 + br_off;
        bf16x8 af[4], bfr[4];
#pragma unroll
        for (int m = 0; m < 4; ++m) af[m] = *reinterpret_cast<const bf16x8*>(ab + m * 512);
#pragma unroll
        for (int n = 0; n < 4; ++n) bfr[n] = *reinterpret_cast<const bf16x8*>(bb + n * 512);
#pragma unroll
        for (int m = 0; m < 4; ++m)
#pragma unroll
            for (int n = 0; n < 4; ++n)
                acc[m][n] = mfma16(af[m], bfr[n], acc[m][n]);
        asm volatile("s_waitcnt vmcnt(0)" ::: "memory");
        __syncthreads();
        buf ^= 1;
    }
}

// ---------------------------------------------------------------------------
// Kernel 3: QKV projection GEMM. 768 blocks (XCD-chunked). Unswapped
// (coalesced epilogue stores). Outputs fp8 e4m3: Q pre-scaled by
// 0.125*log2(e); V transposed [B,H,64,N].
__global__ __launch_bounds__(256) void qkv_gemm_kernel(const __bf16* __restrict__ xb,
                                                       const __bf16* __restrict__ wt,
                                                       unsigned char* __restrict__ q,
                                                       unsigned char* __restrict__ k,
                                                       unsigned char* __restrict__ vt) {
    __shared__ __align__(16) __bf16 abuf[2 * 4096];
    __shared__ __align__(16) __bf16 bbuf[2 * 4096];

    const int bid = blockIdx.x;
    const int vb = (bid & 7) * 96 + (bid >> 3);
    const int by = vb % 12, bx = vb / 12;

    f32x4 acc[4][4] = {};
    gemm_tile_main<24>(xb, 768, bx * 128, wt, 768, by * 128, abuf, bbuf, acc);

    const int lane = threadIdx.x & 63, wave = threadIdx.x >> 6;
    const int lr = lane & 15, lg = lane >> 4;
    const int wr = wave >> 1, wc = wave & 1;
    const int bi = (bx * 128) >> 12;
    const int nbase = (bx * 128) & 4095;

    const float QSCALE = 0.125f * 1.44269504089f;   // fold log2(e): softmax uses exp2

#pragma unroll
    for (int n = 0; n < 4; ++n) {
        const int col0 = by * 128 + wc * 64 + n * 16;
        const int mtx = col0 >> 9;
        const int h   = (col0 >> 6) & 7;
        const int d0  = (col0 & 63) + lr;
        const size_t hb = (size_t)(bi * 8 + h);
#pragma unroll
        for (int m = 0; m < 4; ++m) {
            const int nn = nbase + wr * 64 + m * 16 + lg * 4;
            if (mtx == 0) {
#pragma unroll
                for (int r = 0; r < 4; ++r) {
                    float v = acc[m][n][r] * QSCALE;
                    int p = __builtin_amdgcn_cvt_pk_fp8_f32(v, v, 0, 0);
                    q[((hb * 4096 + nn + r) << 6) + d0] = (unsigned char)(p & 0xFF);
                }
            } else if (mtx == 1) {
#pragma unroll
                for (int r = 0; r < 4; ++r) {
                    float v = acc[m][n][r];
                    int p = __builtin_amdgcn_cvt_pk_fp8_f32(v, v, 0, 0);
                    k[((hb * 4096 + nn + r) << 6) + d0] = (unsigned char)(p & 0xFF);
                }
            } else {
                int vv = 0;
                vv = __builtin_amdgcn_cvt_pk_fp8_f32(acc[m][n][0], acc[m][n][1], vv, 0);
                vv = __builtin_amdgcn_cvt_pk_fp8_f32(acc[m][n][2], acc[m][n][3], vv, 1);
                *reinterpret_cast<int*>(&vt[(hb * 64 + d0) * 4096 + nn]) = vv;
            }
        }
    }
}

// ---------------------------------------------------------------------------
// Kernel 4: flash attention, FP8 (round-15 version, verified fastest).
// 8 waves x 32q x 32k, 4 waves/SIMD, triple-buffered 4KB K/V slots,
// counted vmcnt(1), raw s_barrier, sigma-permuted K staging keeps P
// in-register; 16B-chunk XOR swizzle on staging source; b64 fragment reads.
__global__ __launch_bounds__(512, 4) void attn_kernel(const unsigned char* __restrict__ q,
                                                      const unsigned char* __restrict__ k,
                                                      const unsigned char* __restrict__ vt,
                                                      __bf16* __restrict__ o) {
    const int lane = threadIdx.x & 63, wave = threadIdx.x >> 6;
    const int lr = lane & 15, lg = lane >> 4;
    const int qg = wave >> 1, kh = wave & 1;

    const int bid  = blockIdx.x;
    const int vbid = (bid & 7) * 64 + (bid >> 3);
    const int qtile = vbid & 31;
    const int bh    = vbid >> 5;
    const int qbase = qtile * 128 + qg * 32;

    const unsigned char* Qh = q  + (size_t)bh * N_ * 64;
    const unsigned char* Kh = k  + (size_t)bh * N_ * 64;
    const unsigned char* Vh = vt + (size_t)bh * 64 * N_;

    __shared__ __align__(16) char smem[24576];
    char* kb0 = smem;            // 3 K slots x 4KB
    char* vb0 = smem + 12288;    // 3 V slots x 4KB

    // staging source offsets (per lane): K with row-sigma + chunk swizzle,
    // V with chunk swizzle only. chunk swizzle x(r) = (r&3)^((r>>2)&3).
    int ksrcOff = 0;
    size_t vsrcOff = 0;
    if (wave < 4) {
        int ci = wave * 64 + lane;
        int r = ci >> 2, c = ci & 3;
        int sig = ((r >> 4) & 1) * 32 + ((r >> 2) & 3) * 8 + ((r >> 5) & 1) * 4 + (r & 3);
        ksrcOff = sig * 64 + ((c ^ ((r & 3) ^ ((r >> 2) & 3))) << 4);
    } else {
        int ci = (wave - 4) * 64 + lane;
        int r = ci >> 2, c = ci & 3;
        vsrcOff = (size_t)r * 4096 + ((c ^ ((r & 3) ^ ((r >> 2) & 3))) << 4);
    }

    auto stageK = [&](int slot, int jt) {   // waves 0-3, 1 GLDS16 each
        if (wave < 4)
            GLDS16(Kh + (size_t)jt * 4096 + ksrcOff, kb0 + slot * 4096 + wave * 1024);
    };
    auto stageV = [&](int slot, int jt) {   // waves 4-7, 1 GLDS16 each
        if (wave >= 4)
            GLDS16(Vh + vsrcOff + jt * 64, vb0 + slot * 4096 + (wave - 4) * 1024);
    };

    // fragment read offsets (swizzled, b64)
    int kaddr[2][2], vaddr[4];
#pragma unroll
    for (int kc = 0; kc < 2; ++kc)
#pragma unroll
        for (int c2 = 0; c2 < 2; ++c2) {
            int row = (kh + 2 * c2) * 16 + lr;
            int x = (row & 3) ^ ((row >> 2) & 3);
            kaddr[kc][c2] = row * 64 + (((kc * 2 + (lg >> 1)) ^ x) << 4) + ((lg & 1) << 3);
        }
#pragma unroll
    for (int cbv = 0; cbv < 4; ++cbv) {
        int row = cbv * 16 + lr;
        int x = (row & 3) ^ ((row >> 2) & 3);
        vaddr[cbv] = row * 64 + (((kh * 2 + (lg >> 1)) ^ x) << 4) + ((lg & 1) << 3);
    }

    long long qf[2][2];
#pragma unroll
    for (int f = 0; f < 2; ++f)
#pragma unroll
        for (int kc = 0; kc < 2; ++kc)
            qf[f][kc] = *reinterpret_cast<const long long*>(
                Qh + (size_t)(qbase + f * 16 + lr) * 64 + kc * 32 + lg * 8);

    f32x4 acc[2][4] = {};
    f32x4 accl[2] = {};
    const long long ONES8 = 0x3838383838383838LL;   // 8x fp8 e4m3 1.0

    f32x4 s[2][2];         // 32q x 32k logits (s-slot groups kh, kh+2)
    long long pk[2];       // previous tile's P as fp8x8 PV A-fragments

    auto QK = [&](const char* kb) {
        __builtin_amdgcn_s_setprio(1);
#pragma unroll
        for (int kc = 0; kc < 2; ++kc) {
#pragma unroll
            for (int c2 = 0; c2 < 2; ++c2) {
                long long bk = *reinterpret_cast<const long long*>(kb + kaddr[kc][c2]);
#pragma unroll
                for (int f = 0; f < 2; ++f) {
                    if (kc == 0) s[f][c2] = mfma_fp8(bk, qf[f][0], {});
                    else         s[f][c2] = mfma_fp8(bk, qf[f][1], s[f][c2]);
                }
            }
        }
        __builtin_amdgcn_s_setprio(0);
    };
    auto EXP = [&]() {   // s -> pk (fp8); partial lsum via matrix pipe
#pragma unroll
        for (int f = 0; f < 2; ++f) {
            float p0 = __builtin_amdgcn_exp2f(s[f][0][0]);
            float p1 = __builtin_amdgcn_exp2f(s[f][0][1]);
            float p2 = __builtin_amdgcn_exp2f(s[f][0][2]);
            float p3 = __builtin_amdgcn_exp2f(s[f][0][3]);
            float p4 = __builtin_amdgcn_exp2f(s[f][1][0]);
            float p5 = __builtin_amdgcn_exp2f(s[f][1][1]);
            float p6 = __builtin_amdgcn_exp2f(s[f][1][2]);
            float p7 = __builtin_amdgcn_exp2f(s[f][1][3]);
            int lo = 0, hi = 0;
            lo = __builtin_amdgcn_cvt_pk_fp8_f32(p0, p1, lo, 0);
            lo = __builtin_amdgcn_cvt_pk_fp8_f32(p2, p3, lo, 1);
            hi = __builtin_amdgcn_cvt_pk_fp8_f32(p4, p5, hi, 0);
            hi = __builtin_amdgcn_cvt_pk_fp8_f32(p6, p7, hi, 1);
            pk[f] = (long long)(unsigned int)lo | ((long long)hi << 32);
            accl[f] = mfma_fp8(pk[f], ONES8, accl[f]);
        }
    };
    auto PV = [&](const char* vb) {   // consumes pk; V chunk kc = kh
        __builtin_amdgcn_s_setprio(1);
#pragma unroll
        for (int cbv = 0; cbv < 4; ++cbv) {
            long long bv = *reinterpret_cast<const long long*>(vb + vaddr[cbv]);
#pragma unroll
            for (int f = 0; f < 2; ++f)
                acc[f][cbv] = mfma_fp8(pk[f], bv, acc[f][cbv]);
        }
        __builtin_amdgcn_s_setprio(0);
    };

    auto kslotp = [&](int sl) { return (const char*)(kb0 + sl * 4096); };
    auto vslotp = [&](int sl) { return (const char*)(vb0 + sl * 4096); };

    // one pipelined iteration: stage K(t+2), V(t+1); compute tile t;
    // keep this iter's load (1/wave) in flight; raw barrier.
    auto ITER = [&](int kr, int kw, int ktile, int vr, int vw, int vtile) {
        stageK(kw, ktile);
        stageV(vw, vtile);
        QK(kslotp(kr));
        PV(vslotp(vr));
        EXP();
        asm volatile("s_waitcnt vmcnt(1)" ::: "memory");
        __builtin_amdgcn_s_barrier();
    };

    // ---- prologue: K(0)->k0, K(1)->k1, V(0)->v0; full drain.
    stageK(0, 0); stageK(1, 1); stageV(0, 0);
    asm volatile("s_waitcnt vmcnt(0)" ::: "memory");
    __builtin_amdgcn_s_barrier();

    // ---- iter 0 (no previous tile): stage K(2)->k2, V(1)->v1.
    stageK(2, 2); stageV(1, 1);
    QK(kslotp(0));
    EXP();
    asm volatile("s_waitcnt vmcnt(1)" ::: "memory");
    __builtin_amdgcn_s_barrier();

    // ---- iters 1..60, unrolled by 3 for compile-time slot rotation
    for (int t = 0; t < 20; ++t) {
        const int a = 3 * t + 1;
        ITER(1, 0, a + 2, 0, 2, a + 1);   // jt = a
        ITER(2, 1, a + 3, 1, 0, a + 2);   // jt = a+1
        ITER(0, 2, a + 4, 2, 1, a + 3);   // jt = a+2
    }
    // ---- jt = 61: stage K(63)->k0, V(62)->v2
    ITER(1, 0, 63, 0, 2, 62);

    // ---- jt = 62: only V(63) left to stage; full drain (tail discipline)
    stageV(0, 63);
    QK(kslotp(2));
    PV(vslotp(1));
    EXP();
    asm volatile("s_waitcnt vmcnt(0)" ::: "memory");
    __builtin_amdgcn_s_barrier();

    // ---- jt = 63
    QK(kslotp(0));
    PV(vslotp(2));
    EXP();
    asm volatile("s_waitcnt vmcnt(0)" ::: "memory");
    __builtin_amdgcn_s_barrier();

    // ---- final PV for tile 63 (V63 in v0)
    PV(vslotp(0));
    __syncthreads();     // all waves done with K/V buffers; LDS reusable

    // ---- cross-wave combine: kh=1 writes partials (acc bf16, lsum f32),
    // kh=0 combines and writes output.
    char* exa = smem + qg * 4096;            // acc partials: 64 lanes x 64B
    char* exl = smem + 16384 + qg * 2048;    // lsum partials: 64 lanes x 32B
    if (kh == 1) {
#pragma unroll
        for (int f = 0; f < 2; ++f) {
#pragma unroll
            for (int cbv = 0; cbv < 4; ++cbv) {
                bf16x4 p4;
#pragma unroll
                for (int r = 0; r < 4; ++r) p4[r] = (__bf16)acc[f][cbv][r];
                *reinterpret_cast<bf16x4*>(exa + lane * 64 + (f * 4 + cbv) * 8) = p4;
            }
            *reinterpret_cast<f32x4*>(exl + lane * 32 + f * 16) = accl[f];
        }
    }
    __syncthreads();

    if (kh == 0) {
        const int b = bh >> 3, h = bh & 7;
#pragma unroll
        for (int f = 0; f < 2; ++f) {
            f32x4 lp = *reinterpret_cast<const f32x4*>(exl + lane * 32 + f * 16);
            f32x4 inv;
#pragma unroll
            for (int r = 0; r < 4; ++r) inv[r] = 1.f / (accl[f][r] + lp[r]);
#pragma unroll
            for (int cbv = 0; cbv < 4; ++cbv) {
                bf16x4 ap = *reinterpret_cast<const bf16x4*>(exa + lane * 64 + (f * 4 + cbv) * 8);
#pragma unroll
                for (int r = 0; r < 4; ++r) {
                    const int row = b * N_ + qbase + f * 16 + lg * 4 + r;
                    o[(size_t)row * 512 + h * 64 + cbv * 16 + lr] =
                        (__bf16)((acc[f][cbv][r] + (float)ap[r]) * inv[r]);
                }
            }
        }
    }
}

// ---------------------------------------------------------------------------
// Kernel 5: output projection GEMM (unswapped, coalesced stores). 384 blocks.
__global__ __launch_bounds__(256) void out_gemm_kernel(const __bf16* __restrict__ ob,
                                                       const __bf16* __restrict__ wot,
                                                       const float* __restrict__ bo,
                                                       float* __restrict__ out) {
    __shared__ __align__(16) __bf16 abuf[2 * 4096];
    __shared__ __align__(16) __bf16 bbuf[2 * 4096];

    const int bid = blockIdx.x;
    const int vb = (bid & 7) * 48 + (bid >> 3);
    const int by = vb % 6, bx = vb / 6;

    f32x4 acc[4][4] = {};
    gemm_tile_main<16>(ob, 512, bx * 128, wot, 512, by * 128, abuf, bbuf, acc);

    const int lane = threadIdx.x & 63, wave = threadIdx.x >> 6;
    const int lr = lane & 15, lg = lane >> 4;
    const int wr = wave >> 1, wc = wave & 1;

#pragma unroll
    for (int n = 0; n < 4; ++n) {
        const int col = by * 128 + wc * 64 + n * 16 + lr;
        const float bias = bo[col];
#pragma unroll
        for (int m = 0; m < 4; ++m) {
            const int row0 = bx * 128 + wr * 64 + m * 16 + lg * 4;
#pragma unroll
            for (int r = 0; r < 4; ++r)
                out[(size_t)(row0 + r) * 768 + col] = acc[m][n][r] + bias;
        }
    }
}

// ---------------------------------------------------------------------------
extern "C" void kernel_launch(void* const* d_in, const int* in_sizes, int n_in,
                              void* d_out, int out_size, void* d_ws, size_t ws_size,
                              hipStream_t stream) {
    const float* x  = (const float*)d_in[0];
    const float* Wq = (const float*)d_in[1];
    const float* Wk = (const float*)d_in[2];
    const float* Wv = (const float*)d_in[3];
    const float* Wo = (const float*)d_in[4];
    const float* bo = (const float*)d_in[5];
    float* out = (float*)d_out;

    char* ws = (char*)d_ws;
    __bf16* xb  = (__bf16*)(ws);                                  // 12,582,912
    __bf16* wt  = (__bf16*)(ws + 12582912);                       //  2,359,296
    __bf16* wot = (__bf16*)(ws + 12582912 + 2359296);             //    786,432
    char*   p0  = ws + 12582912 + 2359296 + 786432;               // 15,728,640
    unsigned char* qw  = (unsigned char*)(p0);                    //  4,194,304 (fp8)
    unsigned char* kw  = (unsigned char*)(p0 + 4194304);          //  4,194,304 (fp8)
    unsigned char* vtw = (unsigned char*)(p0 + 2 * 4194304);      //  4,194,304 (fp8)
    __bf16* obf = (__bf16*)(p0 + 3 * (size_t)4194304);            //  8,388,608
    // total ws use: ~36.7 MB

    prep_kernel<<<6528, 256, 0, stream>>>(x, xb, Wq, Wk, Wv, Wo, wt, wot);
    qkv_gemm_kernel<<<768, 256, 0, stream>>>(xb, wt, qw, kw, vtw);
    attn_kernel<<<512, 512, 0, stream>>>(qw, kw, vtw, obf);
    out_gemm_kernel<<<384, 256, 0, stream>>>(obf, wot, bo, out);
}